// Round 15
// baseline (878.278 us; speedup 1.0000x reference)
//
#include <hip/hip_runtime.h>
#include <hip/hip_cooperative_groups.h>
#include <hip/hip_bf16.h>
#include <math.h>

namespace cg = cooperative_groups;

#define NNODES 8192
#define NEDGES 262144
#define INDIM  512
#define H1     256
#define H2     64
#define LSTR   132

typedef __attribute__((ext_vector_type(8))) short bf16x8;
typedef __attribute__((ext_vector_type(4))) float f32x4;

static __device__ __forceinline__ float bf2f(unsigned short u) {
    return __uint_as_float((unsigned)u << 16);
}
static __device__ __forceinline__ unsigned short f2bf(float f) {
    __hip_bfloat16 h = __float2bfloat16(f);
    return *(unsigned short*)&h;
}

// ---------------- gemm tile device fn (r6-validated 64x64 MFMA pattern) ----------

template<int K, int MT, int NT, int NOUT>
__device__ __forceinline__ void gemm_tile(const short* __restrict__ A, const short* __restrict__ BT,
                                          const float* __restrict__ scale, short* __restrict__ out,
                                          int bx, int by, int tid) {
    constexpr int AM = MT / 64;
    constexpr int BN = NT / 16;
    const int lane = tid & 63;
    const int wid  = tid >> 6;
    const int i0 = by * MT + wid * (MT / 4);
    const int j0 = bx * NT;
    const int fr = lane & 15;
    const int kg = lane >> 4;

    f32x4 acc[AM][BN] = {};
    for (int k0 = 0; k0 < K; k0 += 32) {
        bf16x8 a[AM], b[BN];
#pragma unroll
        for (int m = 0; m < AM; m++)
            a[m] = *(const bf16x8*)&A[(size_t)(i0 + m * 16 + fr) * K + k0 + kg * 8];
#pragma unroll
        for (int n = 0; n < BN; n++)
            b[n] = *(const bf16x8*)&BT[(size_t)(j0 + n * 16 + fr) * K + k0 + kg * 8];
#pragma unroll
        for (int m = 0; m < AM; m++)
#pragma unroll
            for (int n = 0; n < BN; n++)
                acc[m][n] = __builtin_amdgcn_mfma_f32_16x16x32_bf16(a[m], b[n], acc[m][n], 0, 0, 0);
    }

    const int col = lane & 15;
    const int rg4 = (lane >> 4) * 4;
#pragma unroll
    for (int m = 0; m < AM; m++)
#pragma unroll
        for (int r = 0; r < 4; r++) {
            int row = i0 + m * 16 + rg4 + r;
            float sc = scale[row];
#pragma unroll
            for (int n = 0; n < BN; n++)
                out[(size_t)row * NOUT + j0 + n * 16 + col] = f2bf(acc[m][n][r] * sc);
        }
}

// ---------------- coop prologue: prep..agg64 (everything but decoder) --------------
// 1024 blocks x 256 (__launch_bounds__(256,4): 4 blocks/CU, 16 waves/CU; LDS 1 KB).
// Decoder deliberately EXCLUDED: it needs full wave oversubscription (r14 lesson:
// coop-resident decoder wrote 256 MB at 600 GB/s, 24% occupancy).

__global__ __launch_bounds__(256, 4) void prologue_kernel(
    const float* __restrict__ features,
    const float* __restrict__ W1, const float* __restrict__ W2,
    const int* __restrict__ src, const int* __restrict__ dst,
    int* deg_out, int* deg_in, int* cursor,          // aliased trio: no __restrict__
    int* __restrict__ row_start, float* __restrict__ norm_out, float* __restrict__ norm_in,
    int* __restrict__ sorted_src,
    __hip_bfloat16* __restrict__ featb, __hip_bfloat16* __restrict__ w1t,
    __hip_bfloat16* __restrict__ w2t,
    const float* __restrict__ b1, const float* __restrict__ b2,
    __hip_bfloat16* __restrict__ xwb, __hip_bfloat16* __restrict__ hb,
    __hip_bfloat16* __restrict__ hwb, __hip_bfloat16* __restrict__ zb) {

    cg::grid_group grid = cg::this_grid();
    __shared__ int part[256];
    const int tid  = threadIdx.x;
    const int gtid = blockIdx.x * 256 + tid;        // 0..262143
    const int lane = tid & 63;
    const int widx = tid >> 6;

    // ---- phase 0: zero counter trio + feature cast + weight transposes ----
    if (gtid < 6144) ((int4*)deg_out)[gtid] = make_int4(0, 0, 0, 0);
#pragma clang loop unroll(disable)
    for (int t = gtid; t < NNODES * INDIM / 4; t += 262144) {
        float4 v = ((const float4*)features)[t];
        ushort4 o;
        o.x = f2bf(v.x); o.y = f2bf(v.y); o.z = f2bf(v.z); o.w = f2bf(v.w);
        ((ushort4*)featb)[t] = o;
    }
    if (gtid < INDIM * H1) {
        int k = gtid / H1, c = gtid % H1;
        w1t[(size_t)c * INDIM + k] = __float2bfloat16(W1[gtid]);
    }
    if (gtid < H1 * H2) {
        int k = gtid / H2, c = gtid % H2;
        w2t[(size_t)c * H1 + k] = __float2bfloat16(W2[gtid]);
    }
    grid.sync();

    // ---- phase 1: degree count (1 edge/thread) ----
    atomicAdd(&deg_out[src[gtid]], 1);
    atomicAdd(&deg_in[dst[gtid]], 1);
    grid.sync();

    // ---- phase 2: exclusive scan + norms (block 0; 256 threads x 32 nodes) ----
    if (blockIdx.x == 0) {
        int s = 0;
        for (int u = 0; u < 32; u++) s += deg_in[tid * 32 + u];
        part[tid] = s; __syncthreads();
        for (int off = 1; off < 256; off <<= 1) {
            int x = part[tid];
            if (tid >= off) x += part[tid - off];
            __syncthreads();
            part[tid] = x;
            __syncthreads();
        }
        int run = part[tid] - s;
        for (int u = 0; u < 32; u++) {
            int n = tid * 32 + u;
            int d = deg_in[n];
            row_start[n] = run; run += d;
            norm_in[n]  = 1.0f / sqrtf(fmaxf((float)d, 1.0f));
            norm_out[n] = 1.0f / sqrtf(fmaxf((float)deg_out[n], 1.0f));
        }
        if (tid == 255) row_start[NNODES] = run;
    }
    grid.sync();

    // ---- phase 3: bucket scatter (1 edge/thread) + gemm1 (blocks 0..511) ----
    {
        int d = dst[gtid];
        int p = atomicAdd(&cursor[d], 1);
        sorted_src[row_start[d] + p] = src[gtid];
    }
    if (blockIdx.x < 512)
        gemm_tile<INDIM, 64, 64, H1>((const short*)featb, (const short*)w1t, norm_out,
                                     (short*)xwb, blockIdx.x & 3, blockIdx.x >> 2, tid);
    grid.sync();

    // ---- phase 4: agg256 (4096 waves x 2 nodes, r9 body) ----
    {
        const ushort4* msg = (const ushort4*)xwb;
        int wave = (blockIdx.x << 2) | widx;
        for (int n = wave; n < NNODES; n += 4096) {
            int e0 = row_start[n], e1 = row_start[n + 1];
            float ax = 0.f, ay = 0.f, az = 0.f, aw = 0.f;
            int e = e0;
            for (; e + 1 < e1; e += 2) {
                int s0 = sorted_src[e], s1 = sorted_src[e + 1];
                ushort4 v0 = msg[(size_t)s0 * 64 + lane];
                ushort4 v1 = msg[(size_t)s1 * 64 + lane];
                ax += bf2f(v0.x) + bf2f(v1.x);
                ay += bf2f(v0.y) + bf2f(v1.y);
                az += bf2f(v0.z) + bf2f(v1.z);
                aw += bf2f(v0.w) + bf2f(v1.w);
            }
            if (e < e1) {
                ushort4 v0 = msg[(size_t)sorted_src[e] * 64 + lane];
                ax += bf2f(v0.x); ay += bf2f(v0.y); az += bf2f(v0.z); aw += bf2f(v0.w);
            }
            float ni = norm_in[n];
            float4 bb = ((const float4*)b1)[lane];
            ushort4 o;
            o.x = f2bf(fmaxf(ax * ni + bb.x, 0.f));
            o.y = f2bf(fmaxf(ay * ni + bb.y, 0.f));
            o.z = f2bf(fmaxf(az * ni + bb.z, 0.f));
            o.w = f2bf(fmaxf(aw * ni + bb.w, 0.f));
            ((ushort4*)hb)[(size_t)n * 64 + lane] = o;
        }
    }
    grid.sync();

    // ---- phase 5: gemm2 (128 tiles on blocks 0..127) ----
    if (blockIdx.x < 128)
        gemm_tile<H1, 64, 64, H2>((const short*)hb, (const short*)w2t, norm_out,
                                  (short*)hwb, 0, blockIdx.x, tid);
    grid.sync();

    // ---- phase 6: agg64 (4096 waves x 2 nodes, r9 body) ----
    {
        const unsigned* msg = (const unsigned*)hwb;
        int wave = (blockIdx.x << 2) | widx;
        int half = lane >> 5, li = lane & 31;
        for (int n = wave; n < NNODES; n += 4096) {
            int e0 = row_start[n], e1 = row_start[n + 1];
            float ax = 0.f, ay = 0.f;
            for (int e = e0 + half; e < e1; e += 2) {
                unsigned u = msg[(size_t)sorted_src[e] * 32 + li];
                ax += bf2f((unsigned short)(u & 0xffff));
                ay += bf2f((unsigned short)(u >> 16));
            }
            ax += __shfl_xor(ax, 32);
            ay += __shfl_xor(ay, 32);
            if (half == 0) {
                float ni = norm_in[n];
                float z0 = ax * ni + b2[2 * li];
                float z1 = ay * ni + b2[2 * li + 1];
                unsigned o = (unsigned)f2bf(z0) | ((unsigned)f2bf(z1) << 16);
                ((unsigned*)zb)[(size_t)n * 32 + li] = o;
            }
        }
    }
}

// ---------------- decoder (r9-validated standalone: full occupancy) ----------------

__global__ __launch_bounds__(256) void decoder_mfma_kernel(const __hip_bfloat16* __restrict__ zbf,
                                                           float* __restrict__ out) {
    __shared__ float lds[4][16 * LSTR];
    const short* zb = (const short*)zbf;
    const int lane = threadIdx.x & 63;
    const int wid  = threadIdx.x >> 6;
    const int i0 = blockIdx.y * 128 + wid * 32;
    const int j0 = blockIdx.x * 128;
    const int fr = lane & 15;
    const int kg = lane >> 4;

    f32x4 acc[2][8] = {};
#pragma unroll
    for (int ks = 0; ks < 2; ks++) {
        bf16x8 a[2], b[8];
#pragma unroll
        for (int m = 0; m < 2; m++)
            a[m] = *(const bf16x8*)&zb[(size_t)(i0 + m * 16 + fr) * H2 + ks * 32 + kg * 8];
#pragma unroll
        for (int n = 0; n < 8; n++)
            b[n] = *(const bf16x8*)&zb[(size_t)(j0 + n * 16 + fr) * H2 + ks * 32 + kg * 8];
#pragma unroll
        for (int m = 0; m < 2; m++)
#pragma unroll
            for (int n = 0; n < 8; n++)
                acc[m][n] = __builtin_amdgcn_mfma_f32_16x16x32_bf16(a[m], b[n], acc[m][n], 0, 0, 0);
    }

    float mx = 0.f;
#pragma unroll
    for (int m = 0; m < 2; m++)
#pragma unroll
        for (int n = 0; n < 8; n++)
#pragma unroll
            for (int r = 0; r < 4; r++)
                mx = fmaxf(mx, fabsf(acc[m][n][r]));
    const bool useExp = __any(mx > 1.0f);

    const int col = lane & 15;
    const int rg4 = (lane >> 4) * 4;
    float* L = lds[wid];
    const int rrow = lane >> 5;
    const int rcol = (lane & 31) * 4;

#pragma unroll
    for (int m = 0; m < 2; m++) {
#pragma unroll
        for (int n = 0; n < 8; n++)
#pragma unroll
            for (int r = 0; r < 4; r++) {
                float x = acc[m][n][r];
                float s;
                if (useExp) {
                    s = 1.f / (1.f + __expf(-x));
                } else {
                    float u = x * x;
                    s = 0.5f + x * (0.25f + u * (-0.0208333333f + u * 0.0020833333f));
                }
                L[(rg4 + r) * LSTR + n * 16 + col] = s;
            }
#pragma unroll
        for (int i = 0; i < 8; i++) {
            int row = i * 2 + rrow;
            float4 v = *(float4*)&L[row * LSTR + rcol];
            *(float4*)&out[(size_t)(i0 + m * 16 + row) * NNODES + j0 + rcol] = v;
        }
    }
}

// ================= fallback path: r9-validated standalone kernels =================

__global__ void prep_kernel(const float* __restrict__ features, __hip_bfloat16* __restrict__ featb,
                            const float* __restrict__ W1, __hip_bfloat16* __restrict__ w1t,
                            const float* __restrict__ W2, __hip_bfloat16* __restrict__ w2t,
                            int* __restrict__ zero_base) {
    int b = blockIdx.x;
    if (b < 4096) {
        int t = b * 256 + threadIdx.x;
        float4 v = ((const float4*)features)[t];
        ushort4 o;
        o.x = f2bf(v.x); o.y = f2bf(v.y); o.z = f2bf(v.z); o.w = f2bf(v.w);
        ((ushort4*)featb)[t] = o;
    } else if (b < 4608) {
        int t = (b - 4096) * 256 + threadIdx.x;
        int k = t / H1, c = t % H1;
        w1t[(size_t)c * INDIM + k] = __float2bfloat16(W1[t]);
    } else if (b < 4672) {
        int t = (b - 4608) * 256 + threadIdx.x;
        int k = t / H2, c = t % H2;
        w2t[(size_t)c * H1 + k] = __float2bfloat16(W2[t]);
    } else {
        int t = (b - 4672) * 256 + threadIdx.x;
        ((int4*)zero_base)[t] = make_int4(0, 0, 0, 0);
    }
}

__global__ void deg_kernel(const int* __restrict__ src, const int* __restrict__ dst,
                           int* deg_out, int* deg_in) {
    int e = blockIdx.x * blockDim.x + threadIdx.x;
    if (e < NEDGES) {
        atomicAdd(&deg_out[src[e]], 1);
        atomicAdd(&deg_in[dst[e]], 1);
    }
}

__global__ __launch_bounds__(1024) void scannorm_kernel(const int* __restrict__ deg_in,
                                                        const int* __restrict__ deg_out,
                                                        int* __restrict__ row_start,
                                                        float* __restrict__ norm_out,
                                                        float* __restrict__ norm_in) {
    __shared__ int part[1024];
    int t = threadIdx.x;
    int v[8]; int s = 0;
#pragma unroll
    for (int u = 0; u < 8; u++) { v[u] = deg_in[t * 8 + u]; s += v[u]; }
    part[t] = s; __syncthreads();
    for (int off = 1; off < 1024; off <<= 1) {
        int x = part[t];
        if (t >= off) x += part[t - off];
        __syncthreads();
        part[t] = x;
        __syncthreads();
    }
    int run = part[t] - s;
#pragma unroll
    for (int u = 0; u < 8; u++) {
        int n = t * 8 + u;
        row_start[n] = run; run += v[u];
        norm_in[n]  = 1.0f / sqrtf(fmaxf((float)v[u], 1.0f));
        norm_out[n] = 1.0f / sqrtf(fmaxf((float)deg_out[n], 1.0f));
    }
    if (t == 1023) row_start[NNODES] = run;
}

__global__ void bucket_kernel(const int* __restrict__ src, const int* __restrict__ dst,
                              const int* __restrict__ row_start,
                              int* cursor, int* __restrict__ sorted_src) {
    int e = blockIdx.x * blockDim.x + threadIdx.x;
    if (e < NEDGES) {
        int d = dst[e];
        int p = atomicAdd(&cursor[d], 1);
        sorted_src[row_start[d] + p] = src[e];
    }
}

template<int K, int MT, int NT, int NOUT>
__global__ __launch_bounds__(256) void gemm_mfma_kernel(const __hip_bfloat16* __restrict__ Af,
                                                        const __hip_bfloat16* __restrict__ BTf,
                                                        const float* __restrict__ scale,
                                                        __hip_bfloat16* __restrict__ outf) {
    gemm_tile<K, MT, NT, NOUT>((const short*)Af, (const short*)BTf, scale, (short*)outf,
                               blockIdx.x, blockIdx.y, threadIdx.x);
}

__global__ void agg256_kernel(const int* __restrict__ row_start, const int* __restrict__ sorted_src,
                              const __hip_bfloat16* __restrict__ msgb, const float* __restrict__ norm_in,
                              const float* __restrict__ bias, __hip_bfloat16* __restrict__ outb) {
    const ushort4* msg = (const ushort4*)msgb;
    int n = blockIdx.x;
    int lane = threadIdx.x;
    int e0 = row_start[n], e1 = row_start[n + 1];
    float ax = 0.f, ay = 0.f, az = 0.f, aw = 0.f;
    int e = e0;
    for (; e + 1 < e1; e += 2) {
        int s0 = sorted_src[e], s1 = sorted_src[e + 1];
        ushort4 v0 = msg[(size_t)s0 * 64 + lane];
        ushort4 v1 = msg[(size_t)s1 * 64 + lane];
        ax += bf2f(v0.x) + bf2f(v1.x);
        ay += bf2f(v0.y) + bf2f(v1.y);
        az += bf2f(v0.z) + bf2f(v1.z);
        aw += bf2f(v0.w) + bf2f(v1.w);
    }
    if (e < e1) {
        ushort4 v0 = msg[(size_t)sorted_src[e] * 64 + lane];
        ax += bf2f(v0.x); ay += bf2f(v0.y); az += bf2f(v0.z); aw += bf2f(v0.w);
    }
    float ni = norm_in[n];
    float4 bb = ((const float4*)bias)[lane];
    ushort4 o;
    o.x = f2bf(fmaxf(ax * ni + bb.x, 0.f));
    o.y = f2bf(fmaxf(ay * ni + bb.y, 0.f));
    o.z = f2bf(fmaxf(az * ni + bb.z, 0.f));
    o.w = f2bf(fmaxf(aw * ni + bb.w, 0.f));
    ((ushort4*)outb)[(size_t)n * 64 + lane] = o;
}

__global__ void agg64_kernel(const int* __restrict__ row_start, const int* __restrict__ sorted_src,
                             const __hip_bfloat16* __restrict__ msgb, const float* __restrict__ norm_in,
                             const float* __restrict__ bias, __hip_bfloat16* __restrict__ outb) {
    const unsigned* msg = (const unsigned*)msgb;
    int n = blockIdx.x;
    int lane = threadIdx.x;
    int half = lane >> 5, li = lane & 31;
    int e0 = row_start[n], e1 = row_start[n + 1];
    float ax = 0.f, ay = 0.f;
    for (int e = e0 + half; e < e1; e += 2) {
        unsigned u = msg[(size_t)sorted_src[e] * 32 + li];
        ax += bf2f((unsigned short)(u & 0xffff));
        ay += bf2f((unsigned short)(u >> 16));
    }
    ax += __shfl_xor(ax, 32);
    ay += __shfl_xor(ay, 32);
    if (half == 0) {
        float ni = norm_in[n];
        float z0 = ax * ni + bias[2 * li];
        float z1 = ay * ni + bias[2 * li + 1];
        unsigned o = (unsigned)f2bf(z0) | ((unsigned)f2bf(z1) << 16);
        ((unsigned*)outb)[(size_t)n * 32 + li] = o;
    }
}

// ---------------- launcher ----------------

extern "C" void kernel_launch(void* const* d_in, const int* in_sizes, int n_in,
                              void* d_out, int out_size, void* d_ws, size_t ws_size,
                              hipStream_t stream) {
    const float* features = (const float*)d_in[0];
    const int*   src      = (const int*)d_in[1];
    const int*   dst      = (const int*)d_in[2];
    const float* W1       = (const float*)d_in[3];
    const float* b1       = (const float*)d_in[4];
    const float* W2       = (const float*)d_in[5];
    const float* b2       = (const float*)d_in[6];
    float* out = (float*)d_out;

    char* p = (char*)d_ws;
    auto alloc = [&](size_t bytes) -> void* {
        void* q = (void*)p;
        p += (bytes + 255) & ~(size_t)255;
        return q;
    };
    int*   deg_out_i  = (int*)alloc(NNODES * 4);   // contiguous trio
    int*   deg_in_i   = (int*)alloc(NNODES * 4);
    int*   cursor     = (int*)alloc(NNODES * 4);
    int*   row_start  = (int*)alloc((NNODES + 1) * 4);
    float* norm_out   = (float*)alloc(NNODES * 4);
    float* norm_in    = (float*)alloc(NNODES * 4);
    int*   sorted_src = (int*)alloc(NEDGES * 4);
    __hip_bfloat16* featb = (__hip_bfloat16*)alloc((size_t)NNODES * INDIM * 2);
    __hip_bfloat16* w1t   = (__hip_bfloat16*)alloc((size_t)H1 * INDIM * 2);
    __hip_bfloat16* w2t   = (__hip_bfloat16*)alloc((size_t)H2 * H1 * 2);
    __hip_bfloat16* xwb   = (__hip_bfloat16*)alloc((size_t)NNODES * H1 * 2);
    __hip_bfloat16* hb    = (__hip_bfloat16*)alloc((size_t)NNODES * H1 * 2);
    __hip_bfloat16* hwb   = (__hip_bfloat16*)alloc((size_t)NNODES * H2 * 2);
    __hip_bfloat16* zb    = (__hip_bfloat16*)alloc((size_t)NNODES * H2 * 2);

    void* args[] = {
        (void*)&features, (void*)&W1, (void*)&W2,
        (void*)&src, (void*)&dst, (void*)&deg_out_i, (void*)&deg_in_i, (void*)&cursor,
        (void*)&row_start, (void*)&norm_out, (void*)&norm_in, (void*)&sorted_src,
        (void*)&featb, (void*)&w1t, (void*)&w2t, (void*)&b1, (void*)&b2,
        (void*)&xwb, (void*)&hb, (void*)&hwb, (void*)&zb
    };
    hipError_t err = hipLaunchCooperativeKernel((const void*)prologue_kernel,
                                                dim3(1024), dim3(256), args, 0, stream);
    if (err != hipSuccess) {
        // fallback: r9-validated path
        prep_kernel<<<4696, 256, 0, stream>>>(features, featb, W1, w1t, W2, w2t, deg_out_i);
        deg_kernel<<<NEDGES / 256, 256, 0, stream>>>(src, dst, deg_out_i, deg_in_i);
        scannorm_kernel<<<1, 1024, 0, stream>>>(deg_in_i, deg_out_i, row_start, norm_out, norm_in);
        bucket_kernel<<<NEDGES / 256, 256, 0, stream>>>(src, dst, row_start, cursor, sorted_src);
        gemm_mfma_kernel<INDIM, 64, 64, H1><<<dim3(H1 / 64, NNODES / 64), 256, 0, stream>>>(
            featb, w1t, norm_out, xwb);
        agg256_kernel<<<NNODES, 64, 0, stream>>>(row_start, sorted_src, xwb, norm_in, b1, hb);
        gemm_mfma_kernel<H1, 64, 64, H2><<<dim3(1, NNODES / 64), 256, 0, stream>>>(
            hb, w2t, norm_out, hwb);
        agg64_kernel<<<NNODES, 64, 0, stream>>>(row_start, sorted_src, hwb, norm_in, b2, zb);
    }

    decoder_mfma_kernel<<<dim3(NNODES / 128, NNODES / 128), 256, 0, stream>>>(zb, out);
}

// Round 16
// 185.931 us; speedup vs baseline: 4.7237x; 4.7237x over previous
//
#include <hip/hip_runtime.h>
#include <hip/hip_bf16.h>
#include <math.h>

#define NNODES 8192
#define NEDGES 262144
#define INDIM  512
#define H1     256
#define H2     64
#define LSTR   132

typedef __attribute__((ext_vector_type(8))) short bf16x8;
typedef __attribute__((ext_vector_type(4))) float f32x4;

static __device__ __forceinline__ float bf2f(unsigned short u) {
    return __uint_as_float((unsigned)u << 16);
}
static __device__ __forceinline__ unsigned short f2bf(float f) {
    __hip_bfloat16 h = __float2bfloat16(f);
    return *(unsigned short*)&h;
}

// ---------------- K2: prep (cast/transposes) + deg, fused via block ranges ---------
// Counter trio zeroed by the preceding hipMemsetAsync (stream-ordered).
// blocks [0,4096): featb cast; [4096,4608): W1->W1T (transposed, rows=cols of W1);
// [4608,4672): W2 straight bf16 cast KEEPING [k][j] layout (coalesced dot reads);
// [4672,5696): degree atomics.

__global__ void prepdeg_kernel(const float* __restrict__ features, __hip_bfloat16* __restrict__ featb,
                               const float* __restrict__ W1, __hip_bfloat16* __restrict__ w1t,
                               const float* __restrict__ W2, __hip_bfloat16* __restrict__ w2b,
                               const int* __restrict__ src, const int* __restrict__ dst,
                               int* deg_out, int* deg_in) {
    int b = blockIdx.x;
    if (b < 4096) {
        int t = b * 256 + threadIdx.x;
        float4 v = ((const float4*)features)[t];
        ushort4 o;
        o.x = f2bf(v.x); o.y = f2bf(v.y); o.z = f2bf(v.z); o.w = f2bf(v.w);
        ((ushort4*)featb)[t] = o;
    } else if (b < 4608) {
        int t = (b - 4096) * 256 + threadIdx.x;   // t < INDIM*H1
        int k = t / H1, c = t % H1;
        w1t[(size_t)c * INDIM + k] = __float2bfloat16(W1[t]);
    } else if (b < 4672) {
        int t = (b - 4608) * 256 + threadIdx.x;   // t < H1*H2
        w2b[t] = __float2bfloat16(W2[t]);         // straight cast, [k][j] layout
    } else {
        int e = (b - 4672) * 256 + threadIdx.x;   // e < NEDGES
        atomicAdd(&deg_out[src[e]], 1);
        atomicAdd(&deg_in[dst[e]], 1);
    }
}

// ---------------- K3: scan + norms (single block, r9-validated) ----------------

__global__ __launch_bounds__(1024) void scannorm_kernel(const int* __restrict__ deg_in,
                                                        const int* __restrict__ deg_out,
                                                        int* __restrict__ row_start,
                                                        float* __restrict__ norm_out,
                                                        float* __restrict__ norm_in) {
    __shared__ int part[1024];
    int t = threadIdx.x;
    int v[8]; int s = 0;
#pragma unroll
    for (int u = 0; u < 8; u++) { v[u] = deg_in[t * 8 + u]; s += v[u]; }
    part[t] = s; __syncthreads();
    for (int off = 1; off < 1024; off <<= 1) {
        int x = part[t];
        if (t >= off) x += part[t - off];
        __syncthreads();
        part[t] = x;
        __syncthreads();
    }
    int run = part[t] - s;
#pragma unroll
    for (int u = 0; u < 8; u++) {
        int n = t * 8 + u;
        row_start[n] = run; run += v[u];
        norm_in[n]  = 1.0f / sqrtf(fmaxf((float)v[u], 1.0f));
        norm_out[n] = 1.0f / sqrtf(fmaxf((float)deg_out[n], 1.0f));
    }
    if (t == 1023) row_start[NNODES] = run;
}

// ---------------- gemm tile device fn (r6-validated 64x64 MFMA pattern) ----------

template<int K, int MT, int NT, int NOUT>
__device__ __forceinline__ void gemm_tile(const short* __restrict__ A, const short* __restrict__ BT,
                                          const float* __restrict__ scale, short* __restrict__ out,
                                          int bx, int by, int tid) {
    constexpr int AM = MT / 64;
    constexpr int BN = NT / 16;
    const int lane = tid & 63;
    const int wid  = tid >> 6;
    const int i0 = by * MT + wid * (MT / 4);
    const int j0 = bx * NT;
    const int fr = lane & 15;
    const int kg = lane >> 4;

    f32x4 acc[AM][BN] = {};
    for (int k0 = 0; k0 < K; k0 += 32) {
        bf16x8 a[AM], b[BN];
#pragma unroll
        for (int m = 0; m < AM; m++)
            a[m] = *(const bf16x8*)&A[(size_t)(i0 + m * 16 + fr) * K + k0 + kg * 8];
#pragma unroll
        for (int n = 0; n < BN; n++)
            b[n] = *(const bf16x8*)&BT[(size_t)(j0 + n * 16 + fr) * K + k0 + kg * 8];
#pragma unroll
        for (int m = 0; m < AM; m++)
#pragma unroll
            for (int n = 0; n < BN; n++)
                acc[m][n] = __builtin_amdgcn_mfma_f32_16x16x32_bf16(a[m], b[n], acc[m][n], 0, 0, 0);
    }

    const int col = lane & 15;
    const int rg4 = (lane >> 4) * 4;
#pragma unroll
    for (int m = 0; m < AM; m++)
#pragma unroll
        for (int r = 0; r < 4; r++) {
            int row = i0 + m * 16 + rg4 + r;
            float sc = scale[row];
#pragma unroll
            for (int n = 0; n < BN; n++)
                out[(size_t)row * NOUT + j0 + n * 16 + col] = f2bf(acc[m][n][r] * sc);
        }
}

// ---------------- K4: bucket (CSR scatter) + gemm1, fused via block ranges --------

__global__ __launch_bounds__(256) void bucketgemm_kernel(const int* __restrict__ src, const int* __restrict__ dst,
                                                         const int* __restrict__ row_start, int* cursor,
                                                         int* __restrict__ sorted_src,
                                                         const __hip_bfloat16* __restrict__ featb,
                                                         const __hip_bfloat16* __restrict__ w1t,
                                                         const float* __restrict__ norm_out,
                                                         __hip_bfloat16* __restrict__ xwb) {
    int b = blockIdx.x;
    if (b < 1024) {
        int e = b * 256 + threadIdx.x;
        int d = dst[e];
        int p = atomicAdd(&cursor[d], 1);
        sorted_src[row_start[d] + p] = src[e];
    } else {
        int g = b - 1024;                 // 512 gemm blocks: 4 (cols) x 128 (rows)
        gemm_tile<INDIM, 64, 64, H1>((const short*)featb, (const short*)w1t, norm_out,
                                     (short*)xwb, g & 3, g >> 2, threadIdx.x);
    }
}

// ---------------- K5: agg256 + gemm2 fused, 1 wave per node ----------------------
// Gather phase = r9 agg256 body verbatim (identical parallelism & access pattern).
// Dot phase: lane j computes sum_k h[k]*W2[k][j] with W2 in [k][j] bf16 layout ->
// each k-step is ONE coalesced 128 B wave-read, w2b (32 KB) L1-resident.
// (r8's disaster was per-lane [j][k] rows = 64-way uncoalesced. Fixed by layout.)

__global__ void aggfused_kernel(const int* __restrict__ row_start, const int* __restrict__ sorted_src,
                                const __hip_bfloat16* __restrict__ msgb,
                                const float* __restrict__ norm_in, const float* __restrict__ norm_out,
                                const float* __restrict__ b1, const __hip_bfloat16* __restrict__ w2b,
                                __hip_bfloat16* __restrict__ hwb) {
    __shared__ float hs[H1];
    const ushort4* msg = (const ushort4*)msgb;
    const unsigned short* w2 = (const unsigned short*)w2b;
    int n = blockIdx.x;
    int lane = threadIdx.x;
    int e0 = row_start[n], e1 = row_start[n + 1];
    float ax = 0.f, ay = 0.f, az = 0.f, aw = 0.f;
    int e = e0;
    for (; e + 1 < e1; e += 2) {
        int s0 = sorted_src[e], s1 = sorted_src[e + 1];
        ushort4 v0 = msg[(size_t)s0 * 64 + lane];
        ushort4 v1 = msg[(size_t)s1 * 64 + lane];
        ax += bf2f(v0.x) + bf2f(v1.x);
        ay += bf2f(v0.y) + bf2f(v1.y);
        az += bf2f(v0.z) + bf2f(v1.z);
        aw += bf2f(v0.w) + bf2f(v1.w);
    }
    if (e < e1) {
        ushort4 v0 = msg[(size_t)sorted_src[e] * 64 + lane];
        ax += bf2f(v0.x); ay += bf2f(v0.y); az += bf2f(v0.z); aw += bf2f(v0.w);
    }
    float ni = norm_in[n];
    float4 bb = ((const float4*)b1)[lane];
    float4 h;
    h.x = fmaxf(ax * ni + bb.x, 0.f);
    h.y = fmaxf(ay * ni + bb.y, 0.f);
    h.z = fmaxf(az * ni + bb.z, 0.f);
    h.w = fmaxf(aw * ni + bb.w, 0.f);
    *(float4*)&hs[lane * 4] = h;
    __syncthreads();

    float acc = 0.f;
#pragma unroll 8
    for (int k0 = 0; k0 < H1; k0 += 4) {
        float4 hv = *(const float4*)&hs[k0];
        acc += hv.x * bf2f(w2[(k0 + 0) * H2 + lane])
             + hv.y * bf2f(w2[(k0 + 1) * H2 + lane])
             + hv.z * bf2f(w2[(k0 + 2) * H2 + lane])
             + hv.w * bf2f(w2[(k0 + 3) * H2 + lane]);
    }
    hwb[(size_t)n * H2 + lane] = __float2bfloat16(acc * norm_out[n]);
}

// ---------------- K6: agg64 -> zb (bf16, r9-validated) ----------------

__global__ void agg64_kernel(const int* __restrict__ row_start, const int* __restrict__ sorted_src,
                             const __hip_bfloat16* __restrict__ msgb, const float* __restrict__ norm_in,
                             const float* __restrict__ bias, __hip_bfloat16* __restrict__ outb) {
    const unsigned* msg = (const unsigned*)msgb;
    int n = blockIdx.x;
    int lane = threadIdx.x;
    int half = lane >> 5, li = lane & 31;
    int e0 = row_start[n], e1 = row_start[n + 1];
    float ax = 0.f, ay = 0.f;
    for (int e = e0 + half; e < e1; e += 2) {
        unsigned u = msg[(size_t)sorted_src[e] * 32 + li];
        ax += bf2f((unsigned short)(u & 0xffff));
        ay += bf2f((unsigned short)(u >> 16));
    }
    ax += __shfl_xor(ax, 32);
    ay += __shfl_xor(ay, 32);
    if (half == 0) {
        float ni = norm_in[n];
        float z0 = ax * ni + bias[2 * li];
        float z1 = ay * ni + bias[2 * li + 1];
        unsigned o = (unsigned)f2bf(z0) | ((unsigned)f2bf(z1) << 16);
        ((unsigned*)outb)[(size_t)n * 32 + li] = o;
    }
}

// ---------------- K7: decoder = sigmoid(Zb @ Zb^T), r9-validated -----------------

__global__ __launch_bounds__(256) void decoder_mfma_kernel(const __hip_bfloat16* __restrict__ zbf,
                                                           float* __restrict__ out) {
    __shared__ float lds[4][16 * LSTR];
    const short* zb = (const short*)zbf;
    const int lane = threadIdx.x & 63;
    const int wid  = threadIdx.x >> 6;
    const int i0 = blockIdx.y * 128 + wid * 32;
    const int j0 = blockIdx.x * 128;
    const int fr = lane & 15;
    const int kg = lane >> 4;

    f32x4 acc[2][8] = {};
#pragma unroll
    for (int ks = 0; ks < 2; ks++) {
        bf16x8 a[2], b[8];
#pragma unroll
        for (int m = 0; m < 2; m++)
            a[m] = *(const bf16x8*)&zb[(size_t)(i0 + m * 16 + fr) * H2 + ks * 32 + kg * 8];
#pragma unroll
        for (int n = 0; n < 8; n++)
            b[n] = *(const bf16x8*)&zb[(size_t)(j0 + n * 16 + fr) * H2 + ks * 32 + kg * 8];
#pragma unroll
        for (int m = 0; m < 2; m++)
#pragma unroll
            for (int n = 0; n < 8; n++)
                acc[m][n] = __builtin_amdgcn_mfma_f32_16x16x32_bf16(a[m], b[n], acc[m][n], 0, 0, 0);
    }

    float mx = 0.f;
#pragma unroll
    for (int m = 0; m < 2; m++)
#pragma unroll
        for (int n = 0; n < 8; n++)
#pragma unroll
            for (int r = 0; r < 4; r++)
                mx = fmaxf(mx, fabsf(acc[m][n][r]));
    const bool useExp = __any(mx > 1.0f);

    const int col = lane & 15;
    const int rg4 = (lane >> 4) * 4;
    float* L = lds[wid];
    const int rrow = lane >> 5;
    const int rcol = (lane & 31) * 4;

#pragma unroll
    for (int m = 0; m < 2; m++) {
#pragma unroll
        for (int n = 0; n < 8; n++)
#pragma unroll
            for (int r = 0; r < 4; r++) {
                float x = acc[m][n][r];
                float s;
                if (useExp) {
                    s = 1.f / (1.f + __expf(-x));
                } else {
                    float u = x * x;
                    s = 0.5f + x * (0.25f + u * (-0.0208333333f + u * 0.0020833333f));
                }
                L[(rg4 + r) * LSTR + n * 16 + col] = s;
            }
#pragma unroll
        for (int i = 0; i < 8; i++) {
            int row = i * 2 + rrow;
            float4 v = *(float4*)&L[row * LSTR + rcol];
            *(float4*)&out[(size_t)(i0 + m * 16 + row) * NNODES + j0 + rcol] = v;
        }
    }
}

// ---------------- launcher (7 dispatches, all standard launches) -------------------

extern "C" void kernel_launch(void* const* d_in, const int* in_sizes, int n_in,
                              void* d_out, int out_size, void* d_ws, size_t ws_size,
                              hipStream_t stream) {
    const float* features = (const float*)d_in[0];
    const int*   src      = (const int*)d_in[1];
    const int*   dst      = (const int*)d_in[2];
    const float* W1       = (const float*)d_in[3];
    const float* b1       = (const float*)d_in[4];
    const float* W2       = (const float*)d_in[5];
    const float* b2       = (const float*)d_in[6];
    float* out = (float*)d_out;

    char* p = (char*)d_ws;
    auto alloc = [&](size_t bytes) -> void* {
        void* q = (void*)p;
        p += (bytes + 255) & ~(size_t)255;
        return q;
    };
    int*   deg_out_i  = (int*)alloc(NNODES * 4);   // contiguous trio (one memset)
    int*   deg_in_i   = (int*)alloc(NNODES * 4);
    int*   cursor     = (int*)alloc(NNODES * 4);
    int*   row_start  = (int*)alloc((NNODES + 1) * 4);
    float* norm_out   = (float*)alloc(NNODES * 4);
    float* norm_in    = (float*)alloc(NNODES * 4);
    int*   sorted_src = (int*)alloc(NEDGES * 4);
    __hip_bfloat16* featb = (__hip_bfloat16*)alloc((size_t)NNODES * INDIM * 2);
    __hip_bfloat16* w1t   = (__hip_bfloat16*)alloc((size_t)H1 * INDIM * 2);
    __hip_bfloat16* w2b   = (__hip_bfloat16*)alloc((size_t)H1 * H2 * 2);
    __hip_bfloat16* xwb   = (__hip_bfloat16*)alloc((size_t)NNODES * H1 * 2);
    __hip_bfloat16* hwb   = (__hip_bfloat16*)alloc((size_t)NNODES * H2 * 2);
    __hip_bfloat16* zb    = (__hip_bfloat16*)alloc((size_t)NNODES * H2 * 2);

    hipMemsetAsync(deg_out_i, 0, 3 * NNODES * 4, stream);                       // D1
    prepdeg_kernel<<<4672 + NEDGES / 256, 256, 0, stream>>>(                    // D2
        features, featb, W1, w1t, W2, w2b, src, dst, deg_out_i, deg_in_i);
    scannorm_kernel<<<1, 1024, 0, stream>>>(deg_in_i, deg_out_i,                // D3
                                            row_start, norm_out, norm_in);
    bucketgemm_kernel<<<1024 + 512, 256, 0, stream>>>(                          // D4
        src, dst, row_start, cursor, sorted_src, featb, w1t, norm_out, xwb);
    aggfused_kernel<<<NNODES, 64, 0, stream>>>(                                 // D5
        row_start, sorted_src, xwb, norm_in, norm_out, b1, w2b, hwb);
    agg64_kernel<<<NNODES, 64, 0, stream>>>(row_start, sorted_src, hwb,         // D6
                                            norm_in, b2, zb);
    decoder_mfma_kernel<<<dim3(NNODES / 128, NNODES / 128), 256, 0, stream>>>(  // D7
        zb, out);
}

// Round 17
// 164.490 us; speedup vs baseline: 5.3394x; 1.1303x over previous
//
#include <hip/hip_runtime.h>
#include <hip/hip_bf16.h>
#include <math.h>

#define NNODES 8192
#define NEDGES 262144
#define INDIM  512
#define H1     256
#define H2     64

typedef __attribute__((ext_vector_type(8))) short bf16x8;
typedef __attribute__((ext_vector_type(4))) float f32x4;

static __device__ __forceinline__ float bf2f(unsigned short u) {
    return __uint_as_float((unsigned)u << 16);
}
static __device__ __forceinline__ unsigned short f2bf(float f) {
    __hip_bfloat16 h = __float2bfloat16(f);
    return *(unsigned short*)&h;
}

// ---------------- fused prep: zero counters + feature cast + weight transposes ------

__global__ void prep_kernel(const float* __restrict__ features, __hip_bfloat16* __restrict__ featb,
                            const float* __restrict__ W1, __hip_bfloat16* __restrict__ w1t,
                            const float* __restrict__ W2, __hip_bfloat16* __restrict__ w2t,
                            int* __restrict__ zero_base) {
    int b = blockIdx.x;
    if (b < 4096) {
        int t = b * 256 + threadIdx.x;
        float4 v = ((const float4*)features)[t];
        ushort4 o;
        o.x = f2bf(v.x); o.y = f2bf(v.y); o.z = f2bf(v.z); o.w = f2bf(v.w);
        ((ushort4*)featb)[t] = o;
    } else if (b < 4608) {
        int t = (b - 4096) * 256 + threadIdx.x;   // t < INDIM*H1
        int k = t / H1, c = t % H1;
        w1t[(size_t)c * INDIM + k] = __float2bfloat16(W1[t]);
    } else if (b < 4672) {
        int t = (b - 4608) * 256 + threadIdx.x;   // t < H1*H2
        int k = t / H2, c = t % H2;
        w2t[(size_t)c * H1 + k] = __float2bfloat16(W2[t]);
    } else {
        int t = (b - 4672) * 256 + threadIdx.x;   // t < 6144
        ((int4*)zero_base)[t] = make_int4(0, 0, 0, 0);
    }
}

// ---------------- degree / CSR build ----------------

__global__ void deg_kernel(const int* __restrict__ src, const int* __restrict__ dst,
                           int* deg_out, int* deg_in) {
    int e = blockIdx.x * blockDim.x + threadIdx.x;
    if (e < NEDGES) {
        atomicAdd(&deg_out[src[e]], 1);
        atomicAdd(&deg_in[dst[e]], 1);
    }
}

__global__ __launch_bounds__(1024) void scannorm_kernel(const int* __restrict__ deg_in,
                                                        const int* __restrict__ deg_out,
                                                        int* __restrict__ row_start,
                                                        float* __restrict__ norm_out,
                                                        float* __restrict__ norm_in) {
    __shared__ int part[1024];
    int t = threadIdx.x;
    int v[8]; int s = 0;
#pragma unroll
    for (int u = 0; u < 8; u++) { v[u] = deg_in[t * 8 + u]; s += v[u]; }
    part[t] = s; __syncthreads();
    for (int off = 1; off < 1024; off <<= 1) {
        int x = part[t];
        if (t >= off) x += part[t - off];
        __syncthreads();
        part[t] = x;
        __syncthreads();
    }
    int run = part[t] - s;
#pragma unroll
    for (int u = 0; u < 8; u++) {
        int n = t * 8 + u;
        row_start[n] = run; run += v[u];
        norm_in[n]  = 1.0f / sqrtf(fmaxf((float)v[u], 1.0f));
        norm_out[n] = 1.0f / sqrtf(fmaxf((float)deg_out[n], 1.0f));
    }
    if (t == 1023) row_start[NNODES] = run;
}

__global__ void bucket_kernel(const int* __restrict__ src, const int* __restrict__ dst,
                              const int* __restrict__ row_start,
                              int* cursor, int* __restrict__ sorted_src) {
    int e = blockIdx.x * blockDim.x + threadIdx.x;
    if (e < NEDGES) {
        int d = dst[e];
        int p = atomicAdd(&cursor[d], 1);
        sorted_src[row_start[d] + p] = src[e];
    }
}

// ---------------- bf16 MFMA GEMM: out[i][j] = (A @ BT^T)[i][j] * scale[i] (bf16 out) ----

template<int K, int MT, int NT, int NOUT>
__global__ __launch_bounds__(256) void gemm_mfma_kernel(const __hip_bfloat16* __restrict__ Af,
                                                        const __hip_bfloat16* __restrict__ BTf,
                                                        const float* __restrict__ scale,
                                                        __hip_bfloat16* __restrict__ outf) {
    constexpr int AM = MT / 64;
    constexpr int BN = NT / 16;
    const short* A  = (const short*)Af;
    const short* BT = (const short*)BTf;
    short* out = (short*)outf;
    const int lane = threadIdx.x & 63;
    const int wid  = threadIdx.x >> 6;
    const int i0 = blockIdx.y * MT + wid * (MT / 4);
    const int j0 = blockIdx.x * NT;
    const int fr = lane & 15;
    const int kg = lane >> 4;

    f32x4 acc[AM][BN] = {};
    for (int k0 = 0; k0 < K; k0 += 32) {
        bf16x8 a[AM], b[BN];
#pragma unroll
        for (int m = 0; m < AM; m++)
            a[m] = *(const bf16x8*)&A[(size_t)(i0 + m * 16 + fr) * K + k0 + kg * 8];
#pragma unroll
        for (int n = 0; n < BN; n++)
            b[n] = *(const bf16x8*)&BT[(size_t)(j0 + n * 16 + fr) * K + k0 + kg * 8];
#pragma unroll
        for (int m = 0; m < AM; m++)
#pragma unroll
            for (int n = 0; n < BN; n++)
                acc[m][n] = __builtin_amdgcn_mfma_f32_16x16x32_bf16(a[m], b[n], acc[m][n], 0, 0, 0);
    }

    const int col = lane & 15;
    const int rg4 = (lane >> 4) * 4;
#pragma unroll
    for (int m = 0; m < AM; m++)
#pragma unroll
        for (int r = 0; r < 4; r++) {
            int row = i0 + m * 16 + rg4 + r;
            float sc = scale[row];
#pragma unroll
            for (int n = 0; n < BN; n++)
                out[(size_t)row * NOUT + j0 + n * 16 + col] = f2bf(acc[m][n][r] * sc);
        }
}

// ---------------- agg256: gather xwb -> h (relu, bf16) ----------------

__global__ void agg256_kernel(const int* __restrict__ row_start, const int* __restrict__ sorted_src,
                              const __hip_bfloat16* __restrict__ msgb, const float* __restrict__ norm_in,
                              const float* __restrict__ bias, __hip_bfloat16* __restrict__ outb) {
    const ushort4* msg = (const ushort4*)msgb;
    int n = blockIdx.x;
    int lane = threadIdx.x;
    int e0 = row_start[n], e1 = row_start[n + 1];
    float ax = 0.f, ay = 0.f, az = 0.f, aw = 0.f;
    int e = e0;
    for (; e + 1 < e1; e += 2) {
        int s0 = sorted_src[e], s1 = sorted_src[e + 1];
        ushort4 v0 = msg[(size_t)s0 * 64 + lane];
        ushort4 v1 = msg[(size_t)s1 * 64 + lane];
        ax += bf2f(v0.x) + bf2f(v1.x);
        ay += bf2f(v0.y) + bf2f(v1.y);
        az += bf2f(v0.z) + bf2f(v1.z);
        aw += bf2f(v0.w) + bf2f(v1.w);
    }
    if (e < e1) {
        ushort4 v0 = msg[(size_t)sorted_src[e] * 64 + lane];
        ax += bf2f(v0.x); ay += bf2f(v0.y); az += bf2f(v0.z); aw += bf2f(v0.w);
    }
    float ni = norm_in[n];
    float4 bb = ((const float4*)bias)[lane];
    ushort4 o;
    o.x = f2bf(fmaxf(ax * ni + bb.x, 0.f));
    o.y = f2bf(fmaxf(ay * ni + bb.y, 0.f));
    o.z = f2bf(fmaxf(az * ni + bb.z, 0.f));
    o.w = f2bf(fmaxf(aw * ni + bb.w, 0.f));
    ((ushort4*)outb)[(size_t)n * 64 + lane] = o;
}

// ---------------- agg64: gather hwb -> zb (bf16) ----------------

__global__ void agg64_kernel(const int* __restrict__ row_start, const int* __restrict__ sorted_src,
                             const __hip_bfloat16* __restrict__ msgb, const float* __restrict__ norm_in,
                             const float* __restrict__ bias, __hip_bfloat16* __restrict__ outb) {
    const unsigned* msg = (const unsigned*)msgb;
    int n = blockIdx.x;
    int lane = threadIdx.x;
    int half = lane >> 5, li = lane & 31;
    int e0 = row_start[n], e1 = row_start[n + 1];
    float ax = 0.f, ay = 0.f;
    for (int e = e0 + half; e < e1; e += 2) {
        unsigned u = msg[(size_t)sorted_src[e] * 32 + li];
        ax += bf2f((unsigned short)(u & 0xffff));
        ay += bf2f((unsigned short)(u >> 16));
    }
    ax += __shfl_xor(ax, 32);
    ay += __shfl_xor(ay, 32);
    if (half == 0) {
        float ni = norm_in[n];
        float z0 = ax * ni + bias[2 * li];
        float z1 = ay * ni + bias[2 * li + 1];
        unsigned o = (unsigned)f2bf(z0) | ((unsigned)f2bf(z1) << 16);
        ((unsigned*)outb)[(size_t)n * 32 + li] = o;
    }
}

// ---------------- decoder: out = sigmoid(Zb @ Zb^T) via bf16 MFMA ----------------

#define LSTR 132

__global__ __launch_bounds__(256) void decoder_mfma_kernel(const __hip_bfloat16* __restrict__ zbf,
                                                           float* __restrict__ out) {
    __shared__ float lds[4][16 * LSTR];
    const short* zb = (const short*)zbf;
    const int lane = threadIdx.x & 63;
    const int wid  = threadIdx.x >> 6;
    const int i0 = blockIdx.y * 128 + wid * 32;
    const int j0 = blockIdx.x * 128;
    const int fr = lane & 15;
    const int kg = lane >> 4;

    f32x4 acc[2][8] = {};
#pragma unroll
    for (int ks = 0; ks < 2; ks++) {
        bf16x8 a[2], b[8];
#pragma unroll
        for (int m = 0; m < 2; m++)
            a[m] = *(const bf16x8*)&zb[(size_t)(i0 + m * 16 + fr) * H2 + ks * 32 + kg * 8];
#pragma unroll
        for (int n = 0; n < 8; n++)
            b[n] = *(const bf16x8*)&zb[(size_t)(j0 + n * 16 + fr) * H2 + ks * 32 + kg * 8];
#pragma unroll
        for (int m = 0; m < 2; m++)
#pragma unroll
            for (int n = 0; n < 8; n++)
                acc[m][n] = __builtin_amdgcn_mfma_f32_16x16x32_bf16(a[m], b[n], acc[m][n], 0, 0, 0);
    }

    float mx = 0.f;
#pragma unroll
    for (int m = 0; m < 2; m++)
#pragma unroll
        for (int n = 0; n < 8; n++)
#pragma unroll
            for (int r = 0; r < 4; r++)
                mx = fmaxf(mx, fabsf(acc[m][n][r]));
    const bool useExp = __any(mx > 1.0f);

    const int col = lane & 15;
    const int rg4 = (lane >> 4) * 4;
    float* L = lds[wid];
    const int rrow = lane >> 5;
    const int rcol = (lane & 31) * 4;

#pragma unroll
    for (int m = 0; m < 2; m++) {
#pragma unroll
        for (int n = 0; n < 8; n++)
#pragma unroll
            for (int r = 0; r < 4; r++) {
                float x = acc[m][n][r];
                float s;
                if (useExp) {
                    s = 1.f / (1.f + __expf(-x));
                } else {
                    float u = x * x;
                    s = 0.5f + x * (0.25f + u * (-0.0208333333f + u * 0.0020833333f));
                }
                L[(rg4 + r) * LSTR + n * 16 + col] = s;
            }
#pragma unroll
        for (int i = 0; i < 8; i++) {
            int row = i * 2 + rrow;
            float4 v = *(float4*)&L[row * LSTR + rcol];
            *(float4*)&out[(size_t)(i0 + m * 16 + row) * NNODES + j0 + rcol] = v;
        }
    }
}

// ---------------- launcher (9 dispatches, r9-exact) ----------------

extern "C" void kernel_launch(void* const* d_in, const int* in_sizes, int n_in,
                              void* d_out, int out_size, void* d_ws, size_t ws_size,
                              hipStream_t stream) {
    const float* features = (const float*)d_in[0];
    const int*   src      = (const int*)d_in[1];
    const int*   dst      = (const int*)d_in[2];
    const float* W1       = (const float*)d_in[3];
    const float* b1       = (const float*)d_in[4];
    const float* W2       = (const float*)d_in[5];
    const float* b2       = (const float*)d_in[6];
    float* out = (float*)d_out;

    char* p = (char*)d_ws;
    auto alloc = [&](size_t bytes) -> void* {
        void* q = (void*)p;
        p += (bytes + 255) & ~(size_t)255;
        return q;
    };
    int*   deg_out_i  = (int*)alloc(NNODES * 4);   // contiguous trio zeroed by prep
    int*   deg_in_i   = (int*)alloc(NNODES * 4);
    int*   cursor     = (int*)alloc(NNODES * 4);
    int*   row_start  = (int*)alloc((NNODES + 1) * 4);
    float* norm_out   = (float*)alloc(NNODES * 4);
    float* norm_in    = (float*)alloc(NNODES * 4);
    int*   sorted_src = (int*)alloc(NEDGES * 4);
    __hip_bfloat16* featb = (__hip_bfloat16*)alloc((size_t)NNODES * INDIM * 2);
    __hip_bfloat16* w1t   = (__hip_bfloat16*)alloc((size_t)H1 * INDIM * 2);
    __hip_bfloat16* w2t   = (__hip_bfloat16*)alloc((size_t)H2 * H1 * 2);
    __hip_bfloat16* xwb   = (__hip_bfloat16*)alloc((size_t)NNODES * H1 * 2);
    __hip_bfloat16* hb    = (__hip_bfloat16*)alloc((size_t)NNODES * H1 * 2);
    __hip_bfloat16* hwb   = (__hip_bfloat16*)alloc((size_t)NNODES * H2 * 2);
    __hip_bfloat16* zb    = (__hip_bfloat16*)alloc((size_t)NNODES * H2 * 2);

    prep_kernel<<<4696, 256, 0, stream>>>(features, featb, W1, w1t, W2, w2t, deg_out_i);
    deg_kernel<<<NEDGES / 256, 256, 0, stream>>>(src, dst, deg_out_i, deg_in_i);
    scannorm_kernel<<<1, 1024, 0, stream>>>(deg_in_i, deg_out_i, row_start, norm_out, norm_in);
    bucket_kernel<<<NEDGES / 256, 256, 0, stream>>>(src, dst, row_start, cursor, sorted_src);

    // layer 1 GEMM (64x64 tiles -> 512 blocks, r6-validated)
    gemm_mfma_kernel<INDIM, 64, 64, H1><<<dim3(H1 / 64, NNODES / 64), 256, 0, stream>>>(
        featb, w1t, norm_out, xwb);
    // agg1 + relu -> h (bf16)
    agg256_kernel<<<NNODES, 64, 0, stream>>>(row_start, sorted_src, xwb, norm_in, b1, hb);
    // layer 2 GEMM: (h @ W2) * norm_out -> hwb
    gemm_mfma_kernel<H1, 64, 64, H2><<<dim3(1, NNODES / 64), 256, 0, stream>>>(
        hb, w2t, norm_out, hwb);
    // agg2 -> zb
    agg64_kernel<<<NNODES, 64, 0, stream>>>(row_start, sorted_src, hwb, norm_in, b2, zb);

    // decoder: sigmoid(zb @ zb^T)
    decoder_mfma_kernel<<<dim3(NNODES / 128, NNODES / 128), 256, 0, stream>>>(zb, out);
}